// Round 2
// baseline (244.693 us; speedup 1.0000x reference)
//
#include <hip/hip_runtime.h>

#define THREADS 256

__device__ __forceinline__ bool lex_lt(float av, int ai, float bv, int bi) {
  return av < bv || (av == bv && ai < bi);
}

// ---------------------------------------------------------------------------
// Precompute e2[k] = sum_d w[d,k]^2 in fp64 (exact to fp32 rounding).
// ---------------------------------------------------------------------------
__global__ __launch_bounds__(THREADS) void vq_pre(
    const float* __restrict__ w, float* __restrict__ e2) {
  int k = blockIdx.x * THREADS + threadIdx.x;
  if (k < 512) {
    double s = 0.0;
#pragma unroll 8
    for (int d = 0; d < 256; ++d) {
      double v = (double)w[d * 512 + k];
      s = fma(v, v, s);
    }
    e2[k] = (float)s;
  }
}

// ---------------------------------------------------------------------------
// Main: per block 64 positions x all 512 codes. Ordering key s = e2 - 2*cross
// (x2 is a shared per-position offset — dropped). Top-2 tracked per row;
// near-ties (gap < 0.05) resolved exactly in fp64.
// ---------------------------------------------------------------------------
__global__ __launch_bounds__(THREADS) void vq_main(
    const float* __restrict__ x, const float* __restrict__ w,
    const float* __restrict__ e2g,
    int* __restrict__ idx_out, float* __restrict__ arg_out) {
  extern __shared__ float smem[];
  float* xs  = smem;            // [256][64] x slab, 64KB
  float* wsm = smem + 16384;    // [8][256]  w D-chunk, 8KB
  float* lv1 = smem + 18432;    // [64] best value
  float* lv2 = smem + 18496;    // [64] 2nd value
  int*   lk1 = (int*)(smem + 18560);  // [64] best idx
  int*   lk2 = (int*)(smem + 18624);  // [64] 2nd idx

  const int tid = threadIdx.x;
  const int blk = blockIdx.x;
  const int b  = blk >> 4;
  const int n0 = (blk & 15) << 6;
  const float* xbase = x + (size_t)b * 262144 + n0;

  // Stage full x slab: xs[d][c] = x[b, d, n0+c]
  {
    int d0 = tid >> 4;
    int c  = (tid & 15) << 2;
#pragma unroll
    for (int rep = 0; rep < 16; ++rep) {
      int d = d0 + (rep << 4);
      float4 v = *(const float4*)(xbase + (size_t)d * 1024 + c);
      *(float4*)&xs[d * 64 + c] = v;
    }
  }

  const int tp = tid >> 5;  // 0..7 -> rows tp*8..tp*8+7
  const int tk = tid & 31;

  // persistent per-row top-2 (lane-local, merged across both k-chunks)
  float rv1[8], rv2[8];
  int   ri1[8], ri2[8];
#pragma unroll
  for (int r = 0; r < 8; ++r) {
    rv1[r] = 3.4e38f; rv2[r] = 3.4e38f;
    ri1[r] = 0x7fffffff; ri2[r] = 0x7fffffff;
  }

  for (int kc = 0; kc < 2; ++kc) {
    const int kbase = kc << 8;
    float acc[8][8];
#pragma unroll
    for (int r = 0; r < 8; ++r)
#pragma unroll
      for (int c = 0; c < 8; ++c) acc[r][c] = 0.f;

    for (int dch = 0; dch < 256; dch += 8) {
      __syncthreads();
      {
        int dr = tid >> 5;
        int cc = (tid & 31) << 3;
        const float* wp = w + (size_t)(dch + dr) * 512 + kbase + cc;
        float4 a0 = *(const float4*)wp;
        float4 a1 = *(const float4*)(wp + 4);
        *(float4*)&wsm[dr * 256 + cc]     = a0;
        *(float4*)&wsm[dr * 256 + cc + 4] = a1;
      }
      __syncthreads();
#pragma unroll
      for (int dd = 0; dd < 8; ++dd) {
        const float* xrow = &xs[(dch + dd) * 64 + tp * 8];
        const float* wrow = &wsm[dd * 256];
        float4 xa = *(const float4*)xrow;
        float4 xb = *(const float4*)(xrow + 4);
        float4 wa = *(const float4*)(wrow + tk * 4);
        float4 wb = *(const float4*)(wrow + 128 + tk * 4);
        float xr[8] = {xa.x, xa.y, xa.z, xa.w, xb.x, xb.y, xb.z, xb.w};
        float wr[8] = {wa.x, wa.y, wa.z, wa.w, wb.x, wb.y, wb.z, wb.w};
#pragma unroll
        for (int r = 0; r < 8; ++r)
#pragma unroll
          for (int c = 0; c < 8; ++c)
            acc[r][c] = fmaf(xr[r], wr[c], acc[r][c]);
      }
    }

    // fold this chunk's 8 candidates per row into lane-local top-2
    float4 e2a = *(const float4*)&e2g[kbase + tk * 4];
    float4 e2b = *(const float4*)&e2g[kbase + 128 + tk * 4];
    float e2r[8] = {e2a.x, e2a.y, e2a.z, e2a.w, e2b.x, e2b.y, e2b.z, e2b.w};
#pragma unroll
    for (int r = 0; r < 8; ++r) {
#pragma unroll
      for (int c = 0; c < 8; ++c) {
        int k = kbase + ((c < 4) ? (tk * 4 + c) : (128 + tk * 4 + (c - 4)));
        float s = fmaf(-2.f, acc[r][c], e2r[c]);
        if (lex_lt(s, k, rv1[r], ri1[r])) {
          rv2[r] = rv1[r]; ri2[r] = ri1[r];
          rv1[r] = s;      ri1[r] = k;
        } else if (lex_lt(s, k, rv2[r], ri2[r])) {
          rv2[r] = s; ri2[r] = k;
        }
      }
    }
  }

  // cross-lane top-2 merge (32 lanes per row group), then publish to LDS
#pragma unroll
  for (int r = 0; r < 8; ++r) {
    float v1 = rv1[r], v2 = rv2[r];
    int   i1 = ri1[r], i2 = ri2[r];
#pragma unroll
    for (int off = 16; off >= 1; off >>= 1) {
      float ov1 = __shfl_xor(v1, off);
      int   oi1 = __shfl_xor(i1, off);
      float ov2 = __shfl_xor(v2, off);
      int   oi2 = __shfl_xor(i2, off);
      bool aFirst = lex_lt(v1, i1, ov1, oi1) || (v1 == ov1 && i1 == oi1);
      float nv1 = aFirst ? v1 : ov1;  int ni1 = aFirst ? i1 : oi1;
      float cv  = aFirst ? ov1 : v1;  int ci  = aFirst ? oi1 : i1;
      float sv  = aFirst ? v2 : ov2;  int si  = aFirst ? i2 : oi2;
      bool cFirst = lex_lt(cv, ci, sv, si);
      v1 = nv1; i1 = ni1;
      v2 = cFirst ? cv : sv; i2 = cFirst ? ci : si;
    }
    if (tk == 0) {
      int row = tp * 8 + r;
      lv1[row] = v1; lv2[row] = v2;
      lk1[row] = i1; lk2[row] = i2;
    }
  }
  __syncthreads();

  // fp64 refinement for near-ties, then write outputs
  if (tid < 64) {
    int row = tid;
    int k1 = lk1[row], k2 = lk2[row];
    int pick = k1;
    if (lv2[row] - lv1[row] < 0.05f) {
      double s1 = 0.0, s2 = 0.0;
#pragma unroll 4
      for (int d = 0; d < 256; ++d) {
        double xv = (double)xs[d * 64 + row];
        double w1 = (double)w[d * 512 + k1];
        double w2 = (double)w[d * 512 + k2];
        double t1 = xv - w1, t2 = xv - w2;
        s1 = fma(t1, t1, s1);
        s2 = fma(t2, t2, s2);
      }
      if (s2 < s1 || (s2 == s1 && k2 < k1)) pick = k2;
    }
    int p = b * 1024 + n0 + row;
    idx_out[p] = pick;
    arg_out[p] = (float)pick;
  }
}

// ---------------------------------------------------------------------------
// Gather: out[b,d,n] = w[d, idx[b,n]]
// ---------------------------------------------------------------------------
__global__ __launch_bounds__(THREADS) void vq_gather(
    const float* __restrict__ w, const int* __restrict__ idx,
    float* __restrict__ out) {
  int t = blockIdx.x * THREADS + threadIdx.x;
  int n4 = t & 255;
  int bd = t >> 8;
  int d = bd & 255;
  int b = bd >> 8;
  int4 id = *(const int4*)&idx[b * 1024 + (n4 << 2)];
  const float* wd = w + d * 512;
  float4 o = make_float4(wd[id.x], wd[id.y], wd[id.z], wd[id.w]);
  *(float4*)&out[(size_t)bd * 1024 + (n4 << 2)] = o;
}

// ---------------------------------------------------------------------------
extern "C" void kernel_launch(void* const* d_in, const int* in_sizes, int n_in,
                              void* d_out, int out_size, void* d_ws, size_t ws_size,
                              hipStream_t stream) {
  const float* x = (const float*)d_in[0];
  const float* w = (const float*)d_in[1];
  float* out  = (float*)d_out;
  float* argf = out + 8388608;
  float* e2 = (float*)d_ws;                 // 512 floats
  int*  idx = (int*)(e2 + 512);             // 32768 ints

  vq_pre<<<2, THREADS, 0, stream>>>(w, e2);
  vq_main<<<512, THREADS, 74752, stream>>>(x, w, e2, idx, argf);
  vq_gather<<<8192, THREADS, 0, stream>>>(w, idx, out);
}

// Round 3
// 178.288 us; speedup vs baseline: 1.3725x; 1.3725x over previous
//
#include <hip/hip_runtime.h>

#define THREADS 256

typedef __attribute__((ext_vector_type(8))) short bf16x8;
typedef __attribute__((ext_vector_type(16))) float f32x16;

__device__ __forceinline__ bool lex_lt(float av, int ai, float bv, int bi) {
  return av < bv || (av == bv && ai < bi);
}

// round-to-nearest-even fp32 -> bf16 (returned as low 16 bits)
__device__ __forceinline__ unsigned bf16_rne(float v) {
  unsigned u = __float_as_uint(v);
  return (u + 0x7fffu + ((u >> 16) & 1u)) >> 16;
}

// ---------------------------------------------------------------------------
// vq_pre: e2[k] (fp64-exact) + transposed bf16-split codebook
// wtil layout: [n][kg(0..31)][hi:8 shorts][lo:8 shorts]  (1024 B per code n)
// ---------------------------------------------------------------------------
__global__ __launch_bounds__(THREADS) void vq_pre(
    const float* __restrict__ w, float* __restrict__ e2,
    short* __restrict__ wtil) {
  int gid = blockIdx.x * THREADS + threadIdx.x;  // 16384 threads
  int n  = gid >> 5;
  int kg = gid & 31;
  double s = 0.0;
  bf16x8 hv, lv;
#pragma unroll
  for (int j = 0; j < 8; ++j) {
    float v = w[(kg * 8 + j) * 512 + n];
    s = fma((double)v, (double)v, s);
    unsigned h = bf16_rne(v);
    float hf = __uint_as_float(h << 16);
    unsigned l = bf16_rne(v - hf);
    hv[j] = (short)h;
    lv[j] = (short)l;
  }
  short* dst = wtil + (size_t)n * 512 + kg * 16;
  *(bf16x8*)dst = hv;
  *(bf16x8*)(dst + 8) = lv;
  // e2 reduction across the 32 lanes sharing n (kg = lane&31)
#pragma unroll
  for (int off = 16; off >= 1; off >>= 1) s += __shfl_xor(s, off);
  if ((threadIdx.x & 31) == 0) e2[n] = (float)s;
}

// ---------------------------------------------------------------------------
// vq_main: block = 64 positions x 512 codes, MFMA bf16 3-split GEMM.
// ---------------------------------------------------------------------------
__global__ __launch_bounds__(THREADS, 2) void vq_main(
    const float* __restrict__ x, const float* __restrict__ w,
    const float* __restrict__ e2g, const short* __restrict__ wtil,
    int* __restrict__ idx_out, float* __restrict__ arg_out) {
  __shared__ char smem_raw[65536 + 4096];
  short* xh = (short*)smem_raw;          // [m][k] swizzled, 32KB
  short* xl = xh + 16384;                // 32KB
  float* tv1 = (float*)(smem_raw + 65536);   // [4][64]
  float* tv2 = tv1 + 256;
  int*   ti1 = (int*)(tv2 + 256);
  int*   ti2 = ti1 + 256;

  const int tid = threadIdx.x;
  const int b  = blockIdx.x >> 4;
  const int n0 = (blockIdx.x & 15) << 6;
  const float* xbase = x + (size_t)b * 262144 + n0;

  // ---- stage x slab as bf16 hi/lo, layout: short off = m*256 + ((kg^(m&7))<<3) + (k&7)
  {
    int d0 = tid >> 4;            // k low part
    int c4 = (tid & 15) << 2;     // m base
#pragma unroll
    for (int rep = 0; rep < 16; ++rep) {
      int k = d0 + (rep << 4);
      float4 v = *(const float4*)(xbase + (size_t)k * 1024 + c4);
      float vv[4] = {v.x, v.y, v.z, v.w};
      int kg = k >> 3, kr = k & 7;
#pragma unroll
      for (int i = 0; i < 4; ++i) {
        int m = c4 + i;
        unsigned h = bf16_rne(vv[i]);
        unsigned l = bf16_rne(vv[i] - __uint_as_float(h << 16));
        int off = m * 256 + (((kg ^ (m & 7)) << 3) | kr);
        xh[off] = (short)h;
        xl[off] = (short)l;
      }
    }
  }
  __syncthreads();

  const int lane = tid & 63;
  const int wv   = tid >> 6;     // wave = n-quarter
  const int ln   = lane & 31;
  const int half = lane >> 5;
  const int wb   = wv << 7;      // wave n base

  f32x16 acc[2][4];
#pragma unroll
  for (int mt = 0; mt < 2; ++mt)
#pragma unroll
    for (int nt = 0; nt < 4; ++nt)
#pragma unroll
      for (int r = 0; r < 16; ++r) acc[mt][nt][r] = 0.f;

  const int m0 = ln, m1 = 32 + ln;
  const int a0base = m0 * 256, a1base = m1 * 256;
  const int a0sw = m0 & 7, a1sw = m1 & 7;

  for (int ch = 0; ch < 16; ++ch) {
    int kg = (ch << 1) + half;
    bf16x8 ah0 = *(const bf16x8*)&xh[a0base + ((kg ^ a0sw) << 3)];
    bf16x8 al0 = *(const bf16x8*)&xl[a0base + ((kg ^ a0sw) << 3)];
    bf16x8 ah1 = *(const bf16x8*)&xh[a1base + ((kg ^ a1sw) << 3)];
    bf16x8 al1 = *(const bf16x8*)&xl[a1base + ((kg ^ a1sw) << 3)];
#pragma unroll
    for (int nt = 0; nt < 4; ++nt) {
      const short* p = wtil + (size_t)(wb + (nt << 5) + ln) * 512 + kg * 16;
      bf16x8 bh = *(const bf16x8*)p;
      bf16x8 bl = *(const bf16x8*)(p + 8);
      acc[0][nt] = __builtin_amdgcn_mfma_f32_32x32x16_bf16(ah0, bh, acc[0][nt], 0, 0, 0);
      acc[0][nt] = __builtin_amdgcn_mfma_f32_32x32x16_bf16(ah0, bl, acc[0][nt], 0, 0, 0);
      acc[0][nt] = __builtin_amdgcn_mfma_f32_32x32x16_bf16(al0, bh, acc[0][nt], 0, 0, 0);
      acc[1][nt] = __builtin_amdgcn_mfma_f32_32x32x16_bf16(ah1, bh, acc[1][nt], 0, 0, 0);
      acc[1][nt] = __builtin_amdgcn_mfma_f32_32x32x16_bf16(ah1, bl, acc[1][nt], 0, 0, 0);
      acc[1][nt] = __builtin_amdgcn_mfma_f32_32x32x16_bf16(al1, bh, acc[1][nt], 0, 0, 0);
    }
  }

  // ---- epilogue: per-row top-2
  float e2v[4];
#pragma unroll
  for (int nt = 0; nt < 4; ++nt) e2v[nt] = e2g[wb + (nt << 5) + ln];

#pragma unroll
  for (int mt = 0; mt < 2; ++mt) {
#pragma unroll
    for (int r = 0; r < 16; ++r) {
      int row = (mt << 5) + (r & 3) + ((r >> 2) << 3) + (half << 2);
      float v1 = 3.4e38f, v2 = 3.4e38f;
      int i1 = 0x7fffffff, i2 = 0x7fffffff;
#pragma unroll
      for (int nt = 0; nt < 4; ++nt) {
        int k = wb + (nt << 5) + ln;
        float s = fmaf(-2.f, acc[mt][nt][r], e2v[nt]);
        if (lex_lt(s, k, v1, i1)) { v2 = v1; i2 = i1; v1 = s; i1 = k; }
        else if (lex_lt(s, k, v2, i2)) { v2 = s; i2 = k; }
      }
      // merge across the 32 lanes sharing this row (xor<32 stays in half)
#pragma unroll
      for (int off = 16; off >= 1; off >>= 1) {
        float ov1 = __shfl_xor(v1, off);
        int   oi1 = __shfl_xor(i1, off);
        float ov2 = __shfl_xor(v2, off);
        int   oi2 = __shfl_xor(i2, off);
        bool aFirst = lex_lt(v1, i1, ov1, oi1);
        float nv1 = aFirst ? v1 : ov1;  int ni1 = aFirst ? i1 : oi1;
        float cv  = aFirst ? ov1 : v1;  int ci  = aFirst ? oi1 : i1;
        float sv  = aFirst ? v2 : ov2;  int si  = aFirst ? i2 : oi2;
        bool cFirst = lex_lt(cv, ci, sv, si);
        v1 = nv1; i1 = ni1;
        v2 = cFirst ? cv : sv; i2 = cFirst ? ci : si;
      }
      if (ln == 0) {
        int s = wv * 64 + row;
        tv1[s] = v1; ti1[s] = i1; tv2[s] = v2; ti2[s] = i2;
      }
    }
  }
  __syncthreads();

  // ---- final cross-wave merge + fp64 refinement (exact x, w from global)
  if (tid < 64) {
    int row = tid;
    float v1 = 3.4e38f, v2 = 3.4e38f;
    int i1 = 0x7fffffff, i2 = 0x7fffffff;
#pragma unroll
    for (int wvv = 0; wvv < 4; ++wvv) {
      int s = wvv * 64 + row;
      float a1 = tv1[s]; int ai = ti1[s];
      float a2 = tv2[s]; int bi = ti2[s];
      if (lex_lt(a1, ai, v1, i1)) { v2 = v1; i2 = i1; v1 = a1; i1 = ai; }
      else if (lex_lt(a1, ai, v2, i2)) { v2 = a1; i2 = ai; }
      if (lex_lt(a2, bi, v1, i1)) { v2 = v1; i2 = i1; v1 = a2; i1 = bi; }
      else if (lex_lt(a2, bi, v2, i2)) { v2 = a2; i2 = bi; }
    }
    int pick = i1;
    if (v2 - v1 < 0.05f) {
      double s1 = 0.0, s2 = 0.0;
      const float* xp = x + (size_t)b * 262144 + n0 + row;
#pragma unroll 4
      for (int k = 0; k < 256; ++k) {
        double xv = (double)xp[(size_t)k * 1024];
        double w1 = (double)w[k * 512 + i1];
        double w2 = (double)w[k * 512 + i2];
        double t1 = xv - w1, t2 = xv - w2;
        s1 = fma(t1, t1, s1);
        s2 = fma(t2, t2, s2);
      }
      if (s2 < s1 || (s2 == s1 && i2 < i1)) pick = i2;
    }
    int p = b * 1024 + n0 + row;
    idx_out[p] = pick;
    arg_out[p] = (float)pick;
  }
}

// ---------------------------------------------------------------------------
// Gather: out[b,d,n] = w[d, idx[b,n]]
// ---------------------------------------------------------------------------
__global__ __launch_bounds__(THREADS) void vq_gather(
    const float* __restrict__ w, const int* __restrict__ idx,
    float* __restrict__ out) {
  int t = blockIdx.x * THREADS + threadIdx.x;
  int n4 = t & 255;
  int bd = t >> 8;
  int d = bd & 255;
  int b = bd >> 8;
  int4 id = *(const int4*)&idx[b * 1024 + (n4 << 2)];
  const float* wd = w + d * 512;
  float4 o = make_float4(wd[id.x], wd[id.y], wd[id.z], wd[id.w]);
  *(float4*)&out[(size_t)bd * 1024 + (n4 << 2)] = o;
}

// ---------------------------------------------------------------------------
extern "C" void kernel_launch(void* const* d_in, const int* in_sizes, int n_in,
                              void* d_out, int out_size, void* d_ws, size_t ws_size,
                              hipStream_t stream) {
  const float* x = (const float*)d_in[0];
  const float* w = (const float*)d_in[1];
  float* out  = (float*)d_out;
  float* argf = out + 8388608;
  float* e2  = (float*)d_ws;                  // 512 floats
  int*   idx = (int*)(e2 + 512);              // 32768 ints
  short* wtil = (short*)(idx + 32768);        // 512*512 shorts = 512 KB

  vq_pre<<<64, THREADS, 0, stream>>>(w, e2, wtil);
  vq_main<<<512, THREADS, 0, stream>>>(x, w, e2, wtil, idx, argf);
  vq_gather<<<8192, THREADS, 0, stream>>>(w, idx, out);
}

// Round 4
// 173.996 us; speedup vs baseline: 1.4063x; 1.0247x over previous
//
#include <hip/hip_runtime.h>

#define THREADS 256

typedef __attribute__((ext_vector_type(8))) short bf16x8;
typedef __attribute__((ext_vector_type(16))) float f32x16;

__device__ __forceinline__ bool lex_lt(float av, int ai, float bv, int bi) {
  return av < bv || (av == bv && ai < bi);
}

// round-to-nearest-even fp32 -> bf16 (returned as low 16 bits)
__device__ __forceinline__ unsigned bf16_rne(float v) {
  unsigned u = __float_as_uint(v);
  return (u + 0x7fffu + ((u >> 16) & 1u)) >> 16;
}

// ---------------------------------------------------------------------------
// vq_pre_w: transposed bf16-split codebook, k-major planes for coalesced
// B-fragment loads:  wh[kg][n][8], wl[kg][n][8]  (each plane 131072 shorts)
// thread (kg, n): n = gid&511 (consecutive lanes = consecutive n -> coalesced
// loads AND stores).
// ---------------------------------------------------------------------------
__global__ __launch_bounds__(THREADS) void vq_pre_w(
    const float* __restrict__ w, short* __restrict__ wtil) {
  int gid = blockIdx.x * THREADS + threadIdx.x;  // 16384 threads
  int n  = gid & 511;
  int kg = gid >> 9;
  bf16x8 hv, lv;
#pragma unroll
  for (int j = 0; j < 8; ++j) {
    float v = w[(kg * 8 + j) * 512 + n];
    unsigned h = bf16_rne(v);
    float hf = __uint_as_float(h << 16);
    unsigned l = bf16_rne(v - hf);
    hv[j] = (short)h;
    lv[j] = (short)l;
  }
  short* dst = wtil + (size_t)gid * 8;   // (kg*512 + n)*8
  *(bf16x8*)dst = hv;
  *(bf16x8*)(dst + 131072) = lv;
}

// ---------------------------------------------------------------------------
// vq_pre_e2: e2[k] = sum_d w[d,k]^2 in fp64 (exact to fp32 rounding).
// ---------------------------------------------------------------------------
__global__ __launch_bounds__(THREADS) void vq_pre_e2(
    const float* __restrict__ w, float* __restrict__ e2) {
  int k = blockIdx.x * THREADS + threadIdx.x;
  if (k < 512) {
    double s = 0.0;
#pragma unroll 8
    for (int d = 0; d < 256; ++d) {
      double v = (double)w[d * 512 + k];
      s = fma(v, v, s);
    }
    e2[k] = (float)s;
  }
}

// ---------------------------------------------------------------------------
// vq_main: block = 64 positions x 512 codes, MFMA bf16 3-split GEMM.
// B loads are now coalesced (k-major wtil planes). K-loop is barrier-free.
// ---------------------------------------------------------------------------
__global__ __launch_bounds__(THREADS, 2) void vq_main(
    const float* __restrict__ x, const float* __restrict__ w,
    const float* __restrict__ e2g, const short* __restrict__ wtil,
    int* __restrict__ idx_out, float* __restrict__ arg_out) {
  __shared__ char smem_raw[65536 + 4096];
  short* xh = (short*)smem_raw;          // [m][k] swizzled, 32KB
  short* xl = xh + 16384;                // 32KB
  float* tv1 = (float*)(smem_raw + 65536);   // [4][64]
  float* tv2 = tv1 + 256;
  int*   ti1 = (int*)(tv2 + 256);
  int*   ti2 = ti1 + 256;

  const int tid = threadIdx.x;
  const int b  = blockIdx.x >> 4;
  const int n0 = (blockIdx.x & 15) << 6;
  const float* xbase = x + (size_t)b * 262144 + n0;

  // ---- stage x slab as bf16 hi/lo, layout: short off = m*256 + ((kg^(m&7))<<3) + (k&7)
  {
    int d0 = tid >> 4;            // k low part
    int c4 = (tid & 15) << 2;     // m base
#pragma unroll
    for (int rep = 0; rep < 16; ++rep) {
      int k = d0 + (rep << 4);
      float4 v = *(const float4*)(xbase + (size_t)k * 1024 + c4);
      float vv[4] = {v.x, v.y, v.z, v.w};
      int kg = k >> 3, kr = k & 7;
#pragma unroll
      for (int i = 0; i < 4; ++i) {
        int m = c4 + i;
        unsigned h = bf16_rne(vv[i]);
        unsigned l = bf16_rne(vv[i] - __uint_as_float(h << 16));
        int off = m * 256 + (((kg ^ (m & 7)) << 3) | kr);
        xh[off] = (short)h;
        xl[off] = (short)l;
      }
    }
  }
  __syncthreads();

  const int lane = tid & 63;
  const int wv   = tid >> 6;     // wave = n-quarter
  const int ln   = lane & 31;
  const int half = lane >> 5;
  const int wb   = wv << 7;      // wave n base

  f32x16 acc[2][4];
#pragma unroll
  for (int mt = 0; mt < 2; ++mt)
#pragma unroll
    for (int nt = 0; nt < 4; ++nt)
#pragma unroll
      for (int r = 0; r < 16; ++r) acc[mt][nt][r] = 0.f;

  const int m0 = ln, m1 = 32 + ln;
  const int a0base = m0 * 256, a1base = m1 * 256;
  const int a0sw = m0 & 7, a1sw = m1 & 7;

  for (int ch = 0; ch < 16; ++ch) {
    int kg = (ch << 1) + half;
    bf16x8 ah0 = *(const bf16x8*)&xh[a0base + ((kg ^ a0sw) << 3)];
    bf16x8 al0 = *(const bf16x8*)&xl[a0base + ((kg ^ a0sw) << 3)];
    bf16x8 ah1 = *(const bf16x8*)&xh[a1base + ((kg ^ a1sw) << 3)];
    bf16x8 al1 = *(const bf16x8*)&xl[a1base + ((kg ^ a1sw) << 3)];
#pragma unroll
    for (int nt = 0; nt < 4; ++nt) {
      // coalesced: lane ln reads 16B at ((kg*512 + n) * 8) shorts
      const short* ph = wtil + (size_t)(((kg << 9) + wb + (nt << 5) + ln) << 3);
      bf16x8 bh = *(const bf16x8*)ph;
      bf16x8 bl = *(const bf16x8*)(ph + 131072);
      acc[0][nt] = __builtin_amdgcn_mfma_f32_32x32x16_bf16(ah0, bh, acc[0][nt], 0, 0, 0);
      acc[0][nt] = __builtin_amdgcn_mfma_f32_32x32x16_bf16(ah0, bl, acc[0][nt], 0, 0, 0);
      acc[0][nt] = __builtin_amdgcn_mfma_f32_32x32x16_bf16(al0, bh, acc[0][nt], 0, 0, 0);
      acc[1][nt] = __builtin_amdgcn_mfma_f32_32x32x16_bf16(ah1, bh, acc[1][nt], 0, 0, 0);
      acc[1][nt] = __builtin_amdgcn_mfma_f32_32x32x16_bf16(ah1, bl, acc[1][nt], 0, 0, 0);
      acc[1][nt] = __builtin_amdgcn_mfma_f32_32x32x16_bf16(al1, bh, acc[1][nt], 0, 0, 0);
    }
  }

  // ---- epilogue: per-row top-2
  float e2v[4];
#pragma unroll
  for (int nt = 0; nt < 4; ++nt) e2v[nt] = e2g[wb + (nt << 5) + ln];

#pragma unroll
  for (int mt = 0; mt < 2; ++mt) {
#pragma unroll
    for (int r = 0; r < 16; ++r) {
      int row = (mt << 5) + (r & 3) + ((r >> 2) << 3) + (half << 2);
      float v1 = 3.4e38f, v2 = 3.4e38f;
      int i1 = 0x7fffffff, i2 = 0x7fffffff;
#pragma unroll
      for (int nt = 0; nt < 4; ++nt) {
        int k = wb + (nt << 5) + ln;
        float s = fmaf(-2.f, acc[mt][nt][r], e2v[nt]);
        if (lex_lt(s, k, v1, i1)) { v2 = v1; i2 = i1; v1 = s; i1 = k; }
        else if (lex_lt(s, k, v2, i2)) { v2 = s; i2 = k; }
      }
      // merge across the 32 lanes sharing this row (xor<32 stays in half)
#pragma unroll
      for (int off = 16; off >= 1; off >>= 1) {
        float ov1 = __shfl_xor(v1, off);
        int   oi1 = __shfl_xor(i1, off);
        float ov2 = __shfl_xor(v2, off);
        int   oi2 = __shfl_xor(i2, off);
        bool aFirst = lex_lt(v1, i1, ov1, oi1);
        float nv1 = aFirst ? v1 : ov1;  int ni1 = aFirst ? i1 : oi1;
        float cv  = aFirst ? ov1 : v1;  int ci  = aFirst ? oi1 : i1;
        float sv  = aFirst ? v2 : ov2;  int si  = aFirst ? i2 : oi2;
        bool cFirst = lex_lt(cv, ci, sv, si);
        v1 = nv1; i1 = ni1;
        v2 = cFirst ? cv : sv; i2 = cFirst ? ci : si;
      }
      if (ln == 0) {
        int s = wv * 64 + row;
        tv1[s] = v1; ti1[s] = i1; tv2[s] = v2; ti2[s] = i2;
      }
    }
  }
  __syncthreads();

  // ---- final cross-wave merge + fp64 refinement (exact x, w from global)
  if (tid < 64) {
    int row = tid;
    float v1 = 3.4e38f, v2 = 3.4e38f;
    int i1 = 0x7fffffff, i2 = 0x7fffffff;
#pragma unroll
    for (int wvv = 0; wvv < 4; ++wvv) {
      int s = wvv * 64 + row;
      float a1 = tv1[s]; int ai = ti1[s];
      float a2 = tv2[s]; int bi = ti2[s];
      if (lex_lt(a1, ai, v1, i1)) { v2 = v1; i2 = i1; v1 = a1; i1 = ai; }
      else if (lex_lt(a1, ai, v2, i2)) { v2 = a1; i2 = ai; }
      if (lex_lt(a2, bi, v1, i1)) { v2 = v1; i2 = i1; v1 = a2; i1 = bi; }
      else if (lex_lt(a2, bi, v2, i2)) { v2 = a2; i2 = bi; }
    }
    int pick = i1;
    if (v2 - v1 < 0.05f) {
      double s1 = 0.0, s2 = 0.0;
      const float* xp = x + (size_t)b * 262144 + n0 + row;
#pragma unroll 4
      for (int k = 0; k < 256; ++k) {
        double xv = (double)xp[(size_t)k * 1024];
        double w1 = (double)w[k * 512 + i1];
        double w2 = (double)w[k * 512 + i2];
        double t1 = xv - w1, t2 = xv - w2;
        s1 = fma(t1, t1, s1);
        s2 = fma(t2, t2, s2);
      }
      if (s2 < s1 || (s2 == s1 && i2 < i1)) pick = i2;
    }
    int p = b * 1024 + n0 + row;
    idx_out[p] = pick;
    arg_out[p] = (float)pick;
  }
}

// ---------------------------------------------------------------------------
// Gather: out[b,d,n] = w[d, idx[b,n]]
// ---------------------------------------------------------------------------
__global__ __launch_bounds__(THREADS) void vq_gather(
    const float* __restrict__ w, const int* __restrict__ idx,
    float* __restrict__ out) {
  int t = blockIdx.x * THREADS + threadIdx.x;
  int n4 = t & 255;
  int bd = t >> 8;
  int d = bd & 255;
  int b = bd >> 8;
  int4 id = *(const int4*)&idx[b * 1024 + (n4 << 2)];
  const float* wd = w + d * 512;
  float4 o = make_float4(wd[id.x], wd[id.y], wd[id.z], wd[id.w]);
  *(float4*)&out[(size_t)bd * 1024 + (n4 << 2)] = o;
}

// ---------------------------------------------------------------------------
extern "C" void kernel_launch(void* const* d_in, const int* in_sizes, int n_in,
                              void* d_out, int out_size, void* d_ws, size_t ws_size,
                              hipStream_t stream) {
  const float* x = (const float*)d_in[0];
  const float* w = (const float*)d_in[1];
  float* out  = (float*)d_out;
  float* argf = out + 8388608;
  float* e2  = (float*)d_ws;                  // 512 floats
  int*   idx = (int*)(e2 + 512);              // 32768 ints
  short* wtil = (short*)(idx + 32768);        // 2 planes x 131072 shorts = 512 KB

  vq_pre_w<<<64, THREADS, 0, stream>>>(w, wtil);
  vq_pre_e2<<<2, THREADS, 0, stream>>>(w, e2);
  vq_main<<<512, THREADS, 0, stream>>>(x, w, e2, wtil, idx, argf);
  vq_gather<<<8192, THREADS, 0, stream>>>(w, idx, out);
}